// Round 12
// baseline (128.304 us; speedup 1.0000x reference)
//
#include <hip/hip_runtime.h>
#include <hip/hip_bf16.h>
#include <stdint.h>

#define N_PTS 4096
#define DIM 512
#define MARGIN_F 0.3f
#define POS_INF_BITS 0x7f800000

typedef short bf16x8 __attribute__((ext_vector_type(8)));
typedef float f32x4 __attribute__((ext_vector_type(4)));

__device__ __forceinline__ unsigned short f2bf(float f) {
    unsigned int b = __float_as_uint(f);
    b += 0x7FFF + ((b >> 16) & 1);   // round-to-nearest-even
    return (unsigned short)(b >> 16);
}

// One wave per row: bf16 copy + exact fp32 norms; zero the output accumulator.
__global__ __launch_bounds__(256) void prep_kernel(
    const float* __restrict__ src, const float* __restrict__ tgt,
    unsigned short* __restrict__ src_bf, unsigned short* __restrict__ tgt_bf,
    float* __restrict__ e1, float* __restrict__ e2,
    float* __restrict__ out)
{
    const int row  = blockIdx.x * 4 + (threadIdx.x >> 6);
    const int lane = threadIdx.x & 63;

    if (blockIdx.x == 0 && threadIdx.x == 0) out[0] = 0.0f;

    const float4* s4 = (const float4*)(src + (size_t)row * DIM);
    const float4* t4 = (const float4*)(tgt + (size_t)row * DIM);
    float4 a0 = s4[lane], a1 = s4[lane + 64];
    float4 b0 = t4[lane], b1 = t4[lane + 64];

    ushort4 u;
    ushort4* so = (ushort4*)(src_bf + (size_t)row * DIM);
    ushort4* to = (ushort4*)(tgt_bf + (size_t)row * DIM);
    u.x = f2bf(a0.x); u.y = f2bf(a0.y); u.z = f2bf(a0.z); u.w = f2bf(a0.w); so[lane] = u;
    u.x = f2bf(a1.x); u.y = f2bf(a1.y); u.z = f2bf(a1.z); u.w = f2bf(a1.w); so[lane + 64] = u;
    u.x = f2bf(b0.x); u.y = f2bf(b0.y); u.z = f2bf(b0.z); u.w = f2bf(b0.w); to[lane] = u;
    u.x = f2bf(b1.x); u.y = f2bf(b1.y); u.z = f2bf(b1.z); u.w = f2bf(b1.w); to[lane + 64] = u;

    float s1 = a0.x*a0.x + a0.y*a0.y + a0.z*a0.z + a0.w*a0.w
             + a1.x*a1.x + a1.y*a1.y + a1.z*a1.z + a1.w*a1.w;
    float s2 = b0.x*b0.x + b0.y*b0.y + b0.z*b0.z + b0.w*b0.w
             + b1.x*b1.x + b1.y*b1.y + b1.z*b1.z + b1.w*b1.w;
    for (int off = 32; off; off >>= 1) {
        s1 += __shfl_down(s1, off);
        s2 += __shfl_down(s2, off);
    }
    if (lane == 0) {
        e1[row] = s1;
        e2[row] = s2;
    }
}

#define BM 128             // wave tile rows
#define WN 64              // wave tile cols
#define BK 32
#define NSTEP (DIM / BK)   // 16
#define NPART 64           // 4096 / WN

// Direct-from-L2 GEMM: NO LDS, NO barriers, NO DMA in the K-loop. Inputs are
// 8 MB total (L2/L3-resident), so each wave loads its MFMA fragments straight
// from global: per lane one 16 B dwordx4 per fragment; the (quad,fr) layout
// makes each 16-lane group cover 64 contiguous bytes per row -> coalesced.
// One wave per block (2048 blocks, 8 waves/CU); explicit distance-1 register
// prefetch: next step's 12 loads issue before this step's 32 MFMAs, yielding
// the hipBLASLt-style interleave (s_waitcnt vmcnt(12), never 0) from the
// compiler's own bookkeeping. Rationale: r9-r11 showed the barrier-coupled
// LDS staging loop is pinned at ~33 us regardless of swizzle/prefetch/tile;
// all pipe floors (MFMA 2 us, LDS 8-10 us, L2 11 us) are far below it.
// Lessons kept: no device fences (r4), no shared-line atomics (r6).
__global__ __launch_bounds__(64, 2) void dist_kernel(
    const unsigned short* __restrict__ src_bf,
    const unsigned short* __restrict__ tgt_bf,
    const float* __restrict__ e1, const float* __restrict__ e2,
    const int* __restrict__ labels,
    float* __restrict__ ap_part, float* __restrict__ an_part)
{
    const int i0 = blockIdx.y * BM;      // 32 row panels
    const int j0 = blockIdx.x * WN;      // 64 col panels
    const int lane = threadIdx.x;        // 0..63
    const int fr = lane & 15;
    const int quad = lane >> 4;

    // fragment base pointers (elements); step s adds s*BK (= 64 B immediates)
    const unsigned short* aBase = src_bf + (size_t)(i0 + fr) * DIM + quad * 8;
    const unsigned short* bBase = tgt_bf + (size_t)(j0 + fr) * DIM + quad * 8;

    f32x4 acc[8][4];
    #pragma unroll
    for (int a = 0; a < 8; a++)
        #pragma unroll
        for (int b = 0; b < 4; b++)
            acc[a][b] = (f32x4){0.f, 0.f, 0.f, 0.f};

    // prologue: step-0 fragments
    bf16x8 afc[8], bfc[4];
    #pragma unroll
    for (int x = 0; x < 8; x++)
        afc[x] = *(const bf16x8*)(aBase + (size_t)x * 16 * DIM);
    #pragma unroll
    for (int x = 0; x < 4; x++)
        bfc[x] = *(const bf16x8*)(bBase + (size_t)x * 16 * DIM);

    #pragma unroll
    for (int s = 0; s < NSTEP; s++) {
        bf16x8 afn[8], bfn[4];
        if (s + 1 < NSTEP) {             // issue next step's loads FIRST
            const int ko = (s + 1) * BK;
            #pragma unroll
            for (int x = 0; x < 8; x++)
                afn[x] = *(const bf16x8*)(aBase + (size_t)x * 16 * DIM + ko);
            #pragma unroll
            for (int x = 0; x < 4; x++)
                bfn[x] = *(const bf16x8*)(bBase + (size_t)x * 16 * DIM + ko);
        }

        #pragma unroll
        for (int tm = 0; tm < 8; tm++)
            #pragma unroll
            for (int tn = 0; tn < 4; tn++)
                acc[tm][tn] = __builtin_amdgcn_mfma_f32_16x16x32_bf16(
                    afc[tm], bfc[tn], acc[tm][tn], 0, 0, 0);

        if (s + 1 < NSTEP) {
            #pragma unroll
            for (int x = 0; x < 8; x++) afc[x] = afn[x];
            #pragma unroll
            for (int x = 0; x < 4; x++) bfc[x] = bfn[x];
        }
    }

    // epilogue: dist -> masked row max/min -> 16-lane reduce -> partial store
    // scalars straight from global (16 KB arrays, L2-hot). Row side is
    // float4/int4-vectorized (quad*4+r consecutive).
    float4 e14[8]; int4 li4[8];
    #pragma unroll
    for (int tm = 0; tm < 8; tm++) {
        e14[tm] = *(const float4*)(e1 + i0 + tm * 16 + quad * 4);
        li4[tm] = *(const int4*)(labels + i0 + tm * 16 + quad * 4);
    }
    float e2v[4]; int ljv[4];
    #pragma unroll
    for (int tn = 0; tn < 4; tn++) {
        e2v[tn] = e2[j0 + tn * 16 + fr];
        ljv[tn] = labels[j0 + tn * 16 + fr];
    }

    const float INF = __int_as_float(POS_INF_BITS);
    const int pcol = blockIdx.x;                         // per-col-wave slot
    #pragma unroll
    for (int tm = 0; tm < 8; tm++) {
        #pragma unroll
        for (int r = 0; r < 4; r++) {
            const int rl = tm * 16 + quad * 4 + r;       // local row 0..127
            const float e1v = ((const float*)&e14[tm])[r];
            const int   liv = ((const int*)&li4[tm])[r];
            float apv = 0.0f;   // neutral for max (dist >= 0)
            float anv = INF;
            #pragma unroll
            for (int tn = 0; tn < 4; tn++) {
                float d = e1v + e2v[tn] - 2.0f * acc[tm][tn][r];
                d = fmaxf(d, 0.0f);
                if (liv == ljv[tn]) apv = fmaxf(apv, d);
                else                anv = fminf(anv, d);
            }
            #pragma unroll
            for (int off = 1; off < 16; off <<= 1) {
                apv = fmaxf(apv, __shfl_xor(apv, off));
                anv = fminf(anv, __shfl_xor(anv, off));
            }
            if (fr == 0) {
                ap_part[(size_t)(i0 + rl) * NPART + pcol] = apv;
                an_part[(size_t)(i0 + rl) * NPART + pcol] = anv;
            }
        }
    }
}

// 32 blocks x 128 threads; thread = one row: reduce 64 partials, relu, sum.
__global__ __launch_bounds__(128) void loss_kernel(
    const float* __restrict__ ap_part, const float* __restrict__ an_part,
    float* __restrict__ out)
{
    const int row = blockIdx.x * 128 + threadIdx.x;
    const float4* a4 = (const float4*)(ap_part + (size_t)row * NPART);
    const float4* n4 = (const float4*)(an_part + (size_t)row * NPART);
    float apv = 0.0f;
    float anv = __int_as_float(POS_INF_BITS);
    #pragma unroll
    for (int i = 0; i < NPART / 4; i++) {
        float4 a = a4[i], n = n4[i];
        apv = fmaxf(apv, fmaxf(fmaxf(a.x, a.y), fmaxf(a.z, a.w)));
        anv = fminf(anv, fminf(fminf(n.x, n.y), fminf(n.z, n.w)));
    }
    float s = fmaxf(apv - anv + MARGIN_F, 0.0f);
    for (int off = 32; off; off >>= 1) s += __shfl_down(s, off);
    __shared__ float red[2];
    if ((threadIdx.x & 63) == 0) red[threadIdx.x >> 6] = s;
    __syncthreads();
    if (threadIdx.x == 0)
        atomicAdd(out, (red[0] + red[1]) / (float)N_PTS);
}

extern "C" void kernel_launch(void* const* d_in, const int* in_sizes, int n_in,
                              void* d_out, int out_size, void* d_ws, size_t ws_size,
                              hipStream_t stream) {
    const float* src   = (const float*)d_in[0];
    const float* tgt   = (const float*)d_in[1];
    const int* labels  = (const int*)d_in[2];

    char* ws = (char*)d_ws;
    const size_t featB = (size_t)N_PTS * DIM * sizeof(unsigned short);  // 4 MiB
    unsigned short* src_bf = (unsigned short*)ws;
    unsigned short* tgt_bf = (unsigned short*)(ws + featB);
    float* e1 = (float*)(ws + 2 * featB);
    float* e2 = e1 + N_PTS;
    float* ap_part = e2 + N_PTS;                 // [N_PTS][NPART] = 1 MiB
    float* an_part = ap_part + (size_t)N_PTS * NPART;

    prep_kernel<<<N_PTS / 4, 256, 0, stream>>>(src, tgt, src_bf, tgt_bf,
                                               e1, e2, (float*)d_out);
    dim3 grid(N_PTS / WN, N_PTS / BM);           // 64 x 32 = 2048 one-wave blocks
    dist_kernel<<<grid, 64, 0, stream>>>(src_bf, tgt_bf, e1, e2, labels,
                                         ap_part, an_part);
    loss_kernel<<<N_PTS / 128, 128, 0, stream>>>(ap_part, an_part, (float*)d_out);
}

// Round 13
// 100.208 us; speedup vs baseline: 1.2804x; 1.2804x over previous
//
#include <hip/hip_runtime.h>
#include <hip/hip_bf16.h>
#include <stdint.h>

#define N_PTS 4096
#define DIM 512
#define MARGIN_F 0.3f
#define POS_INF_BITS 0x7f800000

typedef short bf16x8 __attribute__((ext_vector_type(8)));
typedef float f32x4 __attribute__((ext_vector_type(4)));

__device__ __forceinline__ unsigned short f2bf(float f) {
    unsigned int b = __float_as_uint(f);
    b += 0x7FFF + ((b >> 16) & 1);   // round-to-nearest-even
    return (unsigned short)(b >> 16);
}

// async global->LDS, 16B per lane; LDS dest is wave-uniform base + lane*16
__device__ __forceinline__ void async16(const unsigned short* g, unsigned short* l) {
    __builtin_amdgcn_global_load_lds(
        (const __attribute__((address_space(1))) unsigned int*)g,
        (__attribute__((address_space(3))) unsigned int*)l,
        16, 0, 0);
}

// Raw barrier / waitcnt (hipBLASLt pattern): no vmcnt(0) drain in steady state.
#define RAW_BARRIER()  asm volatile("s_barrier" ::: "memory")
#define WAIT_VM6()     asm volatile("s_waitcnt vmcnt(6)" ::: "memory")
#define WAIT_VM0()     asm volatile("s_waitcnt vmcnt(0)" ::: "memory")

// One wave per row: bf16 copy + exact fp32 norms; zero the output accumulator.
__global__ __launch_bounds__(256) void prep_kernel(
    const float* __restrict__ src, const float* __restrict__ tgt,
    unsigned short* __restrict__ src_bf, unsigned short* __restrict__ tgt_bf,
    float* __restrict__ e1, float* __restrict__ e2,
    float* __restrict__ out)
{
    const int row  = blockIdx.x * 4 + (threadIdx.x >> 6);
    const int lane = threadIdx.x & 63;

    if (blockIdx.x == 0 && threadIdx.x == 0) out[0] = 0.0f;

    const float4* s4 = (const float4*)(src + (size_t)row * DIM);
    const float4* t4 = (const float4*)(tgt + (size_t)row * DIM);
    float4 a0 = s4[lane], a1 = s4[lane + 64];
    float4 b0 = t4[lane], b1 = t4[lane + 64];

    ushort4 u;
    ushort4* so = (ushort4*)(src_bf + (size_t)row * DIM);
    ushort4* to = (ushort4*)(tgt_bf + (size_t)row * DIM);
    u.x = f2bf(a0.x); u.y = f2bf(a0.y); u.z = f2bf(a0.z); u.w = f2bf(a0.w); so[lane] = u;
    u.x = f2bf(a1.x); u.y = f2bf(a1.y); u.z = f2bf(a1.z); u.w = f2bf(a1.w); so[lane + 64] = u;
    u.x = f2bf(b0.x); u.y = f2bf(b0.y); u.z = f2bf(b0.z); u.w = f2bf(b0.w); to[lane] = u;
    u.x = f2bf(b1.x); u.y = f2bf(b1.y); u.z = f2bf(b1.z); u.w = f2bf(b1.w); to[lane + 64] = u;

    float s1 = a0.x*a0.x + a0.y*a0.y + a0.z*a0.z + a0.w*a0.w
             + a1.x*a1.x + a1.y*a1.y + a1.z*a1.z + a1.w*a1.w;
    float s2 = b0.x*b0.x + b0.y*b0.y + b0.z*b0.z + b0.w*b0.w
             + b1.x*b1.x + b1.y*b1.y + b1.z*b1.z + b1.w*b1.w;
    for (int off = 32; off; off >>= 1) {
        s1 += __shfl_down(s1, off);
        s2 += __shfl_down(s2, off);
    }
    if (lane == 0) {
        e1[row] = s1;
        e2[row] = s2;
    }
}

#define BM 128
#define BN 256
#define BK 32
#define NSTEP (DIM / BK)   // 16
#define NPART 64           // 16 col-blocks x 4 col-waves

// r11 fat-wave kernel with ONE barrier per step (was 2). Safety with the
// 3-stage buffer: per step s the order is
//   s_waitcnt vmcnt(6)  -- my 6 DMAs for tile s (issued two windows ago)
//                          drained; tile s+1's 6 still fly
//   s_barrier           -- => ALL waves' tile-s DMA landed, and all waves
//                          finished reading buf (s-1)%3
//   issue tile s+2      -- targets (s+2)%3 == (s-1)%3: safe, readers passed
//   compute tile s      -- reads s%3; in-flight DMAs target (s+1)%3,(s+2)%3
// The old trailing barrier is redundant: the single rendezvous bounds skew.
// r12 lesson: direct-from-L2 fragments are request-rate-bound (16 scattered
// lines per load instr) — LDS staging is the right structure. Lessons kept:
// no device fences (r4), no shared-line atomics (r6), XOR swizzle on the
// global gather (r3/r9: 0 conflicts), >=2 blocks/CU (r8).
__global__ __launch_bounds__(256, 2) void dist_kernel(
    const unsigned short* __restrict__ src_bf,
    const unsigned short* __restrict__ tgt_bf,
    const float* __restrict__ e1, const float* __restrict__ e2,
    const int* __restrict__ labels,
    float* __restrict__ ap_part, float* __restrict__ an_part)
{
    __shared__ unsigned short As[3][BM * BK];   // 3 x 8 KiB
    __shared__ unsigned short Bs[3][BN * BK];   // 3 x 16 KiB
    __shared__ int   li[BM];
    __shared__ int   lj[BN];
    __shared__ float e1s[BM];
    __shared__ float e2s[BN];

    const int i0 = blockIdx.y * BM;
    const int j0 = blockIdx.x * BN;
    const int t = threadIdx.x;
    const int lane = t & 63;
    const int wave = t >> 6;

    lj[t] = labels[j0 + t];
    e2s[t] = e2[j0 + t];
    if (t < BM) { li[t] = labels[i0 + t]; e1s[t] = e1[i0 + t]; }

    // staging: 16B chunks; thread t covers A rows srow, srow+64 and B rows
    // srow, +64, +128, +192. Physical chunk col t&3 holds logical chunk
    // (t&3)^((srow>>1)&3) (same swizzle key for row and row+64k).
    const int srow = t >> 2;                              // 0..63
    const int scol = ((t & 3) ^ ((srow >> 1) & 3)) * 8;   // swizzled source col
    const unsigned short* gA0 = src_bf + (size_t)(i0 + srow) * DIM + scol;
    const unsigned short* gA1 = src_bf + (size_t)(i0 + 64 + srow) * DIM + scol;
    const unsigned short* gB0 = tgt_bf + (size_t)(j0 + srow) * DIM + scol;
    const unsigned short* gB1 = tgt_bf + (size_t)(j0 + 64 + srow) * DIM + scol;
    const unsigned short* gB2 = tgt_bf + (size_t)(j0 + 128 + srow) * DIM + scol;
    const unsigned short* gB3 = tgt_bf + (size_t)(j0 + 192 + srow) * DIM + scol;
    const int aOff0 = wave * 512;            // A rows 0..63 chunk base
    const int aOff1 = 2048 + wave * 512;     // A rows 64..127
    const int bOff0 = wave * 512;            // B rows 0..63
    const int bOff1 = 2048 + wave * 512;     // 64..127
    const int bOff2 = 4096 + wave * 512;     // 128..191
    const int bOff3 = 6144 + wave * 512;     // 192..255

    // wave -> 128x64 subtile: 8x4 of 16x16x32 MFMA; wn = wave*64
    const int wn = wave * 64;
    const int fr = lane & 15;
    const int quad = lane >> 4;
    const int fkey = (fr >> 1) & 3;                       // read-side XOR key
    const int cp = (quad ^ fkey) * 8;                     // physical chunk off

    f32x4 acc[8][4];
    #pragma unroll
    for (int a = 0; a < 8; a++)
        #pragma unroll
        for (int b = 0; b < 4; b++)
            acc[a][b] = (f32x4){0.f, 0.f, 0.f, 0.f};

    // prologue: tiles 0 and 1 -> bufs 0,1 (12 loads in flight)
    #pragma unroll
    for (int p = 0; p < 2; p++) {
        const int kk = p * BK;
        async16(gA0 + kk, &As[p][0] + aOff0);
        async16(gA1 + kk, &As[p][0] + aOff1);
        async16(gB0 + kk, &Bs[p][0] + bOff0);
        async16(gB1 + kk, &Bs[p][0] + bOff1);
        async16(gB2 + kk, &Bs[p][0] + bOff2);
        async16(gB3 + kk, &Bs[p][0] + bOff3);
    }

    #pragma unroll
    for (int s = 0; s < NSTEP; s++) {
        if (s + 1 < NSTEP) {
            WAIT_VM6();    // tile-s DMAs drained; tile s+1's 6 still fly
        } else {
            WAIT_VM0();    // last tile
        }
        RAW_BARRIER();     // all tile-s DMA landed; all reads of (s-1)%3 done

        if (s + 2 < NSTEP) {   // refill buf (s+2)%3 == (s-1)%3 — safe now
            const int kk = (s + 2) * BK;
            const int nb = (s + 2) % 3;
            async16(gA0 + kk, &As[nb][0] + aOff0);
            async16(gA1 + kk, &As[nb][0] + aOff1);
            async16(gB0 + kk, &Bs[nb][0] + bOff0);
            async16(gB1 + kk, &Bs[nb][0] + bOff1);
            async16(gB2 + kk, &Bs[nb][0] + bOff2);
            async16(gB3 + kk, &Bs[nb][0] + bOff3);
        }

        const unsigned short* aa = &As[s % 3][0];
        const unsigned short* bb = &Bs[s % 3][0];
        bf16x8 af[8], bf[4];
        #pragma unroll
        for (int x = 0; x < 8; x++)
            af[x] = *(const bf16x8*)&aa[(x * 16 + fr) * BK + cp];
        #pragma unroll
        for (int x = 0; x < 4; x++)
            bf[x] = *(const bf16x8*)&bb[(wn + x * 16 + fr) * BK + cp];
        #pragma unroll
        for (int tm = 0; tm < 8; tm++)
            #pragma unroll
            for (int tn = 0; tn < 4; tn++)
                acc[tm][tn] = __builtin_amdgcn_mfma_f32_16x16x32_bf16(
                    af[tm], bf[tn], acc[tm][tn], 0, 0, 0);
    }

    // epilogue: dist -> masked row max/min -> 16-lane reduce -> partial store
    const float INF = __int_as_float(POS_INF_BITS);
    const int pcol = blockIdx.x * 4 + wave;              // per-col-wave slot
    #pragma unroll
    for (int tm = 0; tm < 8; tm++) {
        #pragma unroll
        for (int r = 0; r < 4; r++) {
            const int rl = tm * 16 + quad * 4 + r;       // local row 0..127
            const float e1v = e1s[rl];
            const int   liv = li[rl];
            float apv = 0.0f;   // neutral for max (dist >= 0)
            float anv = INF;
            #pragma unroll
            for (int tn = 0; tn < 4; tn++) {
                const int cl = wn + tn * 16 + fr;        // local col 0..255
                float d = e1v + e2s[cl] - 2.0f * acc[tm][tn][r];
                d = fmaxf(d, 0.0f);
                if (liv == lj[cl]) apv = fmaxf(apv, d);
                else               anv = fminf(anv, d);
            }
            #pragma unroll
            for (int off = 1; off < 16; off <<= 1) {
                apv = fmaxf(apv, __shfl_xor(apv, off));
                anv = fminf(anv, __shfl_xor(anv, off));
            }
            if (fr == 0) {
                ap_part[(size_t)(i0 + rl) * NPART + pcol] = apv;
                an_part[(size_t)(i0 + rl) * NPART + pcol] = anv;
            }
        }
    }
}

// 32 blocks x 128 threads; thread = one row: reduce 64 partials, relu, sum.
__global__ __launch_bounds__(128) void loss_kernel(
    const float* __restrict__ ap_part, const float* __restrict__ an_part,
    float* __restrict__ out)
{
    const int row = blockIdx.x * 128 + threadIdx.x;
    const float4* a4 = (const float4*)(ap_part + (size_t)row * NPART);
    const float4* n4 = (const float4*)(an_part + (size_t)row * NPART);
    float apv = 0.0f;
    float anv = __int_as_float(POS_INF_BITS);
    #pragma unroll
    for (int i = 0; i < NPART / 4; i++) {
        float4 a = a4[i], n = n4[i];
        apv = fmaxf(apv, fmaxf(fmaxf(a.x, a.y), fmaxf(a.z, a.w)));
        anv = fminf(anv, fminf(fminf(n.x, n.y), fminf(n.z, n.w)));
    }
    float s = fmaxf(apv - anv + MARGIN_F, 0.0f);
    for (int off = 32; off; off >>= 1) s += __shfl_down(s, off);
    __shared__ float red[2];
    if ((threadIdx.x & 63) == 0) red[threadIdx.x >> 6] = s;
    __syncthreads();
    if (threadIdx.x == 0)
        atomicAdd(out, (red[0] + red[1]) / (float)N_PTS);
}

extern "C" void kernel_launch(void* const* d_in, const int* in_sizes, int n_in,
                              void* d_out, int out_size, void* d_ws, size_t ws_size,
                              hipStream_t stream) {
    const float* src   = (const float*)d_in[0];
    const float* tgt   = (const float*)d_in[1];
    const int* labels  = (const int*)d_in[2];

    char* ws = (char*)d_ws;
    const size_t featB = (size_t)N_PTS * DIM * sizeof(unsigned short);  // 4 MiB
    unsigned short* src_bf = (unsigned short*)ws;
    unsigned short* tgt_bf = (unsigned short*)(ws + featB);
    float* e1 = (float*)(ws + 2 * featB);
    float* e2 = e1 + N_PTS;
    float* ap_part = e2 + N_PTS;                 // [N_PTS][NPART] = 1 MiB
    float* an_part = ap_part + (size_t)N_PTS * NPART;

    prep_kernel<<<N_PTS / 4, 256, 0, stream>>>(src, tgt, src_bf, tgt_bf,
                                               e1, e2, (float*)d_out);
    dim3 grid(N_PTS / BN, N_PTS / BM);           // 16 x 32 = 512 blocks
    dist_kernel<<<grid, 256, 0, stream>>>(src_bf, tgt_bf, e1, e2, labels,
                                          ap_part, an_part);
    loss_kernel<<<N_PTS / 128, 128, 0, stream>>>(ap_part, an_part, (float*)d_out);
}